// Round 18
// baseline (474.001 us; speedup 1.0000x reference)
//
#include <hip/hip_runtime.h>

// MalleConv: all f32. Head feature maps stored PADDED (zero halo).
// feat0p/tmpAp: (4,32,130,136) stride 136, interior [row+1][col+4], CS=17680
// feat1p/tmpBp: (4,32,66,72)   stride 72,  interior [row+1][col+4], CS=4752

#define BATCH 4
#define NCH 32
#define CS128 17680
#define SP128 136
#define CS64 4752
#define SP64 72

__device__ __forceinline__ float fast_tanh(float s) {
  float e = __expf(2.f * s);
  return fmaf(-2.f, __builtin_amdgcn_rcpf(e + 1.f), 1.f);
}

// ---- zero padded head buffers
__global__ void zero_kernel(float* __restrict__ p) {
  int i = blockIdx.x * 256 + threadIdx.x;  // 5608*256 = 1,435,648
  *reinterpret_cast<float4*>(p + (size_t)i * 4) = make_float4(0.f, 0.f, 0.f, 0.f);
}

// ---- prep: pa_w (8,co,ci,9)->(8,ci,9,co); exp_w (320,32)->(32,320); pw_w (o,c)->(c,o)
__global__ void prep_kernel(const float* __restrict__ pa_w, const float* __restrict__ exp_w,
                            const float* __restrict__ pw_w, float* __restrict__ wt,
                            float* __restrict__ ewt, float* __restrict__ pwt) {
  int i = blockIdx.x * 256 + threadIdx.x;
  if (i < 73728) {
    int tap = i % 9; int t = i / 9;
    int ci = t & 31; t >>= 5;
    int co = t & 31; int layer = t >> 5;
    wt[((layer * 32 + ci) * 9 + tap) * 32 + co] = pa_w[i];
  } else if (i < 83968) {
    int j = i - 73728; int ci = j & 31; int o = j >> 5;
    ewt[ci * 320 + o] = exp_w[j];
  } else if (i < 84992) {
    int j = i - 83968; int c = j & 31; int o = j >> 5;
    pwt[c * 32 + o] = pw_w[j];
  }
}

// ---- avgpool k=4: x(B,C,512,512) -> feat0p interior
__global__ void avgpool4_kernel(const float* __restrict__ x, float* __restrict__ outp) {
  int idx = blockIdx.x * 256 + threadIdx.x;
  if (idx >= BATCH * NCH * 128 * 128) return;
  int ow = idx & 127; int t = idx >> 7; int oh = t & 127; int bc = t >> 7;
  const float* src = x + ((size_t)(bc * 512 + oh * 4)) * 512 + ow * 4;
  float s = 0.f;
#pragma unroll
  for (int r = 0; r < 4; r++) {
    float4 v = *reinterpret_cast<const float4*>(src + (size_t)r * 512);
    s += v.x + v.y + v.z + v.w;
  }
  outp[(size_t)bc * CS128 + (size_t)(oh + 1) * SP128 + ow + 4] = s * 0.0625f;
}

// ---- avgpool k=2: feat0p interior -> feat1p interior
__global__ void avgpool2_kernel(const float* __restrict__ inp, float* __restrict__ outp) {
  int idx = blockIdx.x * 256 + threadIdx.x;
  if (idx >= BATCH * NCH * 64 * 64) return;
  int ow = idx & 63; int t = idx >> 6; int oh = t & 63; int bc = t >> 6;
  const float* sp = inp + (size_t)bc * CS128 + (size_t)(2 * oh + 1) * SP128 + 2 * ow + 4;
  float2 a = *reinterpret_cast<const float2*>(sp);
  float2 b = *reinterpret_cast<const float2*>(sp + SP128);
  outp[(size_t)bc * CS64 + (size_t)(oh + 1) * SP64 + ow + 4] = (a.x + a.y + b.x + b.y) * 0.25f;
}

// ---- conv3x3 direct, 2 VERTICAL px/thread (R16 config, no swizzle).
template <int HS, int SP, int CS, int NCO, bool RELU, bool RES>
__global__ __launch_bounds__(256) void conv3x3v_kernel(
    const float* __restrict__ in, const float* __restrict__ wt,
    const float* __restrict__ bias, const float* __restrict__ res,
    float* __restrict__ out) {
  constexpr int TX = HS / 16;
  constexpr int TY = HS / 32;
  constexpr int GROUPS = 32 / NCO;
  int blk = blockIdx.x;
  int g = blk % GROUPS; int rest = blk / GROUPS;
  int b = rest / (TX * TY); int t = rest % (TX * TY);
  int ty = t / TX, tx = t % TX;
  int og = g * NCO;
  int px = threadIdx.x & 15, py = threadIdx.x >> 4;
  int gy = ty * 32 + py * 2, gx = tx * 16 + px;
  size_t pix = (size_t)(gy + 1) * SP + gx + 4;
  const float* inb = in + (size_t)b * 32 * CS + pix;

  float acc0[NCO], acc1[NCO];
#pragma unroll
  for (int o = 0; o < NCO; o++) { acc0[o] = bias[og + o]; acc1[o] = acc0[o]; }

#pragma unroll 2
  for (int ci = 0; ci < 32; ci++) {
    const float* p = inb + (size_t)ci * CS;
    float v[12];
    v[0] = p[-SP - 1];    v[1] = p[-SP];     v[2] = p[-SP + 1];
    v[3] = p[-1];         v[4] = p[0];       v[5] = p[1];
    v[6] = p[SP - 1];     v[7] = p[SP];      v[8] = p[SP + 1];
    v[9] = p[2 * SP - 1]; v[10] = p[2 * SP]; v[11] = p[2 * SP + 1];
    const float* wr = wt + ci * 288 + og;
#pragma unroll
    for (int tap = 0; tap < 9; tap++) {
      const float* wrow = wr + tap * 32;
#pragma unroll
      for (int o = 0; o < NCO; o++) {
        acc0[o] = fmaf(v[tap], wrow[o], acc0[o]);
        acc1[o] = fmaf(v[tap + 3], wrow[o], acc1[o]);
      }
    }
  }

  float* ob = out + (size_t)b * 32 * CS + (size_t)og * CS + pix;
  const float* rb = RES ? (res + (size_t)b * 32 * CS + (size_t)og * CS + pix) : nullptr;
#pragma unroll
  for (int o = 0; o < NCO; o++) {
    float r0 = acc0[o], r1 = acc1[o];
    if (RELU) { r0 = r0 > 0.f ? r0 : 0.01f * r0; r1 = r1 > 0.f ? r1 : 0.01f * r1; }
    if (RES) { r0 += rb[(size_t)o * CS]; r1 += rb[(size_t)o * CS + SP]; }
    ob[(size_t)o * CS] = r0;
    ob[(size_t)o * CS + SP] = r1;
  }
}

// ---- conv3x3 direct 1px (@64, R16 config, no swizzle).
template <int HS, int SP, int CS, int NCO, bool RELU, bool RES>
__global__ __launch_bounds__(256) void conv3x3d_kernel(
    const float* __restrict__ in, const float* __restrict__ wt,
    const float* __restrict__ bias, const float* __restrict__ res,
    float* __restrict__ out) {
  constexpr int TILES = HS / 16;
  constexpr int GROUPS = 32 / NCO;
  int blk = blockIdx.x;
  int g = blk % GROUPS; int rest = blk / GROUPS;
  int b = rest / (TILES * TILES); int t = rest % (TILES * TILES);
  int ty = t / TILES, tx = t % TILES;
  int og = g * NCO;
  int px = threadIdx.x & 15, py = threadIdx.x >> 4;
  int gy = ty * 16 + py, gx = tx * 16 + px;
  size_t pix = (size_t)(gy + 1) * SP + gx + 4;
  const float* inb = in + (size_t)b * 32 * CS + pix;

  float acc[NCO];
#pragma unroll
  for (int o = 0; o < NCO; o++) acc[o] = bias[og + o];

#pragma unroll 2
  for (int ci = 0; ci < 32; ci++) {
    const float* p = inb + (size_t)ci * CS;
    float v[9];
    v[0] = p[-SP - 1]; v[1] = p[-SP]; v[2] = p[-SP + 1];
    v[3] = p[-1];      v[4] = p[0];   v[5] = p[1];
    v[6] = p[SP - 1];  v[7] = p[SP];  v[8] = p[SP + 1];
    const float* wr = wt + ci * 288 + og;
#pragma unroll
    for (int tap = 0; tap < 9; tap++) {
      const float* wrow = wr + tap * 32;
#pragma unroll
      for (int o = 0; o < NCO; o++)
        acc[o] = fmaf(v[tap], wrow[o], acc[o]);
    }
  }

  float* ob = out + (size_t)b * 32 * CS + (size_t)og * CS + pix;
  const float* rb = RES ? (res + (size_t)b * 32 * CS + (size_t)og * CS + pix) : nullptr;
#pragma unroll
  for (int o = 0; o < NCO; o++) {
    float r2 = acc[o];
    if (RELU) r2 = r2 > 0.f ? r2 : 0.01f * r2;
    if (RES) r2 += rb[(size_t)o * CS];
    ob[(size_t)o * CS] = r2;
  }
}

// ---- expander 1x1 (32->320) + fast tanh, padded feat1p input.
__global__ __launch_bounds__(256) void expander_kernel(
    const float* __restrict__ feat, const float* __restrict__ ewt,
    const float* __restrict__ eb, float* __restrict__ wmap) {
  int idx = blockIdx.x * 256 + threadIdx.x;  // 1,310,720
  int wq = idx & 15; int t = idx >> 4;
  int o = t % 320; int rest = t / 320;
  int hb = rest & 63; int b = rest >> 6;
  const float* fp = feat + (size_t)b * 32 * CS64 + (size_t)(hb + 1) * SP64 + 4 + wq * 4;
  float s0 = eb[o];
  float s1 = s0, s2 = s0, s3 = s0;
#pragma unroll 8
  for (int ci = 0; ci < 32; ci++) {
    float4 f = *reinterpret_cast<const float4*>(fp + (size_t)ci * CS64);
    float wv = ewt[ci * 320 + o];
    s0 = fmaf(f.x, wv, s0); s1 = fmaf(f.y, wv, s1);
    s2 = fmaf(f.z, wv, s2); s3 = fmaf(f.w, wv, s3);
  }
  float4 r;
  r.x = fast_tanh(s0); r.y = fast_tanh(s1);
  r.z = fast_tanh(s2); r.w = fast_tanh(s3);
  *reinterpret_cast<float4*>(wmap + (size_t)((b * 64 + hb) * 320 + o) * 64 + wq * 4) = r;
}

// ---- fused flying conv + final 1x1, v9: TWO-PHASE.
// Phase 1: thread = (channel, row, col-half); fly for 32 px via rolling float4
//          window (24 independent float4 loads) -> fly_s LDS.
// Phase 2: thread = (col, row-quad); pw accumulate from LDS (conflict-free).
// Two 16-channel passes; LDS = s_w 10.3KB + fly_s 34.5KB -> 3 blocks/CU.
__global__ __launch_bounds__(256) void fused_fly_pw_kernel(
    const float* __restrict__ x, const float* __restrict__ wmap,
    const float* __restrict__ pwt, const float* __restrict__ pw_b,
    float* __restrict__ out) {
  __shared__ float s_w[8][322];
  __shared__ float fly_s[8][65][17];  // [row][col pad65][c pad17]
  int blk = blockIdx.x;  // ((b*64+hb)*8 + wtile)
  int wtile = blk & 7; int t = blk >> 3; int hb = t & 63; int b = t >> 6;
  int tid = threadIdx.x;

  const float* wsrc = wmap + (size_t)(b * 64 + hb) * 320 * 64 + wtile * 8;
#pragma unroll
  for (int j = 0; j < 10; j++) {
    int idx = j * 256 + tid;
    int tap = idx >> 3, wb8 = idx & 7;
    s_w[wb8][tap] = wsrc[(size_t)tap * 64 + wb8];
  }

  int h0 = hb * 8;
  int base = wtile * 64;
  const float* xb = x + (size_t)b * 32 * 262144;

  // phase-1 map
  int cl = (tid >> 3) & 15;
  int row = tid & 7;
  int half = tid >> 7;
  int cstart = half * 32;
  // phase-2 map
  int col2 = tid & 63, r4 = tid >> 6;

  float acc0[32], acc1[32];
#pragma unroll
  for (int o = 0; o < 32; o++) { acc0[o] = pw_b[o]; acc1[o] = pw_b[o]; }

  for (int pass = 0; pass < 2; pass++) {
    int c = pass * 16 + cl;
    const float* xc = xb + (size_t)c * 262144;
    int hA = h0 + row - 1, hC = h0 + row + 1;
    bool okA = (hA >= 0);            // hA<512 always
    bool okC = (hC < 512);
    const float* pA = xc + (size_t)hA * 512;
    const float* pB = xc + (size_t)(h0 + row) * 512;
    const float* pC = xc + (size_t)hC * 512;

    __syncthreads();  // fly_s free (prev pass done); s_w staged (pass 0)

    int c0 = base + cstart;
    int lc = c0 - 1;
    float lA = 0.f, lB = 0.f, lC = 0.f;
    if (lc >= 0) {
      lA = okA ? pA[lc] : 0.f;
      lB = pB[lc];
      lC = okC ? pC[lc] : 0.f;
    }
    float4 z4 = make_float4(0.f, 0.f, 0.f, 0.f);
    float4 cA = okA ? *reinterpret_cast<const float4*>(pA + c0) : z4;
    float4 cB = *reinterpret_cast<const float4*>(pB + c0);
    float4 cC = okC ? *reinterpret_cast<const float4*>(pC + c0) : z4;

#pragma unroll
    for (int k2 = 0; k2 < 4; k2++) {
      // weights for wb8 = cstart/8 + k2 (covers chunks 2*k2, 2*k2+1)
      int wb8 = (cstart >> 3) + k2;
      const float* wp = &s_w[wb8][c * 10];
      float wv0 = wp[0], wv1 = wp[1], wv2 = wp[2], wv3 = wp[3], wv4 = wp[4];
      float wv5 = wp[5], wv6 = wp[6], wv7 = wp[7], wv8 = wp[8], wv9 = wp[9];
#pragma unroll
      for (int kk = 0; kk < 2; kk++) {
        int k = k2 * 2 + kk;
        float4 nA, nB, nC;
        if (k < 7) {
          int nc = c0 + 4 * (k + 1);
          nA = okA ? *reinterpret_cast<const float4*>(pA + nc) : z4;
          nB = *reinterpret_cast<const float4*>(pB + nc);
          nC = okC ? *reinterpret_cast<const float4*>(pC + nc) : z4;
        } else {
          int rc = c0 + 32;
          bool okR = (rc < 512);
          nA = z4; nB = z4; nC = z4;
          nA.x = (okA && okR) ? pA[rc] : 0.f;
          nB.x = okR ? pB[rc] : 0.f;
          nC.x = (okC && okR) ? pC[rc] : 0.f;
        }
        // 4 px: cols c0+4k+j
        float f0 = wv9, f1 = wv9, f2 = wv9, f3 = wv9;
        f0 = fmaf(lA, wv0, f0);   f0 = fmaf(cA.x, wv1, f0); f0 = fmaf(cA.y, wv2, f0);
        f0 = fmaf(lB, wv3, f0);   f0 = fmaf(cB.x, wv4, f0); f0 = fmaf(cB.y, wv5, f0);
        f0 = fmaf(lC, wv6, f0);   f0 = fmaf(cC.x, wv7, f0); f0 = fmaf(cC.y, wv8, f0);
        f1 = fmaf(cA.x, wv0, f1); f1 = fmaf(cA.y, wv1, f1); f1 = fmaf(cA.z, wv2, f1);
        f1 = fmaf(cB.x, wv3, f1); f1 = fmaf(cB.y, wv4, f1); f1 = fmaf(cB.z, wv5, f1);
        f1 = fmaf(cC.x, wv6, f1); f1 = fmaf(cC.y, wv7, f1); f1 = fmaf(cC.z, wv8, f1);
        f2 = fmaf(cA.y, wv0, f2); f2 = fmaf(cA.z, wv1, f2); f2 = fmaf(cA.w, wv2, f2);
        f2 = fmaf(cB.y, wv3, f2); f2 = fmaf(cB.z, wv4, f2); f2 = fmaf(cB.w, wv5, f2);
        f2 = fmaf(cC.y, wv6, f2); f2 = fmaf(cC.z, wv7, f2); f2 = fmaf(cC.w, wv8, f2);
        f3 = fmaf(cA.z, wv0, f3); f3 = fmaf(cA.w, wv1, f3); f3 = fmaf(nA.x, wv2, f3);
        f3 = fmaf(cB.z, wv3, f3); f3 = fmaf(cB.w, wv4, f3); f3 = fmaf(nB.x, wv5, f3);
        f3 = fmaf(cC.z, wv6, f3); f3 = fmaf(cC.w, wv7, f3); f3 = fmaf(nC.x, wv8, f3);
        int colw = cstart + 4 * k;
        fly_s[row][colw + 0][cl] = f0;
        fly_s[row][colw + 1][cl] = f1;
        fly_s[row][colw + 2][cl] = f2;
        fly_s[row][colw + 3][cl] = f3;
        lA = cA.w; lB = cB.w; lC = cC.w;
        cA = nA; cB = nB; cC = nC;
      }
    }
    __syncthreads();  // fly_s ready

#pragma unroll
    for (int cc = 0; cc < 16; cc++) {
      float fa = fly_s[r4][col2][cc];
      float fb = fly_s[r4 + 4][col2][cc];
      const float* prow = pwt + (pass * 16 + cc) * 32;
#pragma unroll
      for (int o = 0; o < 32; o++) {
        float pw = prow[o];
        acc0[o] = fmaf(fa, pw, acc0[o]);
        acc1[o] = fmaf(fb, pw, acc1[o]);
      }
    }
  }

  float* ob = out + (size_t)b * 32 * 262144 + (size_t)(h0 + r4) * 512 + base + col2;
#pragma unroll
  for (int o = 0; o < 32; o++) {
    ob[(size_t)o * 262144] = acc0[o];
    ob[(size_t)o * 262144 + 2048] = acc1[o];  // row +4
  }
}

extern "C" void kernel_launch(void* const* d_in, const int* in_sizes, int n_in,
                              void* d_out, int out_size, void* d_ws, size_t ws_size,
                              hipStream_t stream) {
  const float* x     = (const float*)d_in[0];
  const float* pa_w  = (const float*)d_in[1];
  const float* pa_b  = (const float*)d_in[2];
  const float* exp_w = (const float*)d_in[3];
  const float* exp_b = (const float*)d_in[4];
  const float* pw_w  = (const float*)d_in[5];
  const float* pw_b  = (const float*)d_in[6];
  float* out = (float*)d_out;
  float* ws  = (float*)d_ws;

  float* feat0p = ws;                    // 4*32*130*136 = 2,263,040
  float* tmpAp  = feat0p + 2263040;      // 2,263,040
  float* feat1p = tmpAp + 2263040;       // 4*32*66*72 = 608,256
  float* wmap   = feat1p + 608256;       // 5,242,880
  float* tmpBp  = wmap;                  // aliases wmap (dead before expander writes)
  float* wt     = wmap + 5242880;        // 73,728
  float* ewt    = wt + 73728;            // 10,240
  float* pwt    = ewt + 10240;           // 1,024

  hipLaunchKernelGGL(zero_kernel, dim3(5608), dim3(256), 0, stream, ws);
  hipLaunchKernelGGL(prep_kernel, dim3(332), dim3(256), 0, stream, pa_w, exp_w, pw_w, wt, ewt, pwt);
  hipLaunchKernelGGL(avgpool4_kernel, dim3(8192), dim3(256), 0, stream, x, feat0p);

  // predictors @128: 2-vert-px, NCO=4 -> 1024 blocks
  for (int i = 0; i < 2; i++) {
    const float* w1 = wt + (size_t)(i * 2 + 0) * 9216;
    const float* b1 = pa_b + (i * 2 + 0) * 32;
    const float* w2 = wt + (size_t)(i * 2 + 1) * 9216;
    const float* b2 = pa_b + (i * 2 + 1) * 32;
    hipLaunchKernelGGL((conv3x3v_kernel<128, SP128, CS128, 4, true, false>),
                       dim3(1024), dim3(256), 0, stream, feat0p, w1, b1, nullptr, tmpAp);
    hipLaunchKernelGGL((conv3x3v_kernel<128, SP128, CS128, 4, false, true>),
                       dim3(1024), dim3(256), 0, stream, tmpAp, w2, b2, feat0p, feat0p);
  }

  hipLaunchKernelGGL(avgpool2_kernel, dim3(2048), dim3(256), 0, stream, feat0p, feat1p);

  // predictors @64: NCO=2 -> 1024 blocks
  for (int i = 2; i < 4; i++) {
    const float* w1 = wt + (size_t)(i * 2 + 0) * 9216;
    const float* b1 = pa_b + (i * 2 + 0) * 32;
    const float* w2 = wt + (size_t)(i * 2 + 1) * 9216;
    const float* b2 = pa_b + (i * 2 + 1) * 32;
    hipLaunchKernelGGL((conv3x3d_kernel<64, SP64, CS64, 2, true, false>),
                       dim3(1024), dim3(256), 0, stream, feat1p, w1, b1, nullptr, tmpBp);
    hipLaunchKernelGGL((conv3x3d_kernel<64, SP64, CS64, 2, false, true>),
                       dim3(1024), dim3(256), 0, stream, tmpBp, w2, b2, feat1p, feat1p);
  }

  hipLaunchKernelGGL(expander_kernel, dim3(5120), dim3(256), 0, stream, feat1p, ewt, exp_b, wmap);

  hipLaunchKernelGGL(fused_fly_pw_kernel, dim3(2048), dim3(256), 0, stream,
                     x, wmap, pwt, pw_b, out);
}

// Round 19
// 399.407 us; speedup vs baseline: 1.1868x; 1.1868x over previous
//
#include <hip/hip_runtime.h>

// MalleConv: all f32. Head feature maps stored PADDED (zero halo).
// feat0p/tmpAp: (4,32,130,136) stride 136, interior [row+1][col+4], CS=17680
// feat1p/tmpBp: (4,32,66,72)   stride 72,  interior [row+1][col+4], CS=4752

#define BATCH 4
#define NCH 32
#define CS128 17680
#define SP128 136
#define CS64 4752
#define SP64 72

__device__ __forceinline__ float fast_tanh(float s) {
  float e = __expf(2.f * s);
  return fmaf(-2.f, __builtin_amdgcn_rcpf(e + 1.f), 1.f);
}

// ---- zero padded head buffers
__global__ void zero_kernel(float* __restrict__ p) {
  int i = blockIdx.x * 256 + threadIdx.x;  // 5608*256 = 1,435,648
  *reinterpret_cast<float4*>(p + (size_t)i * 4) = make_float4(0.f, 0.f, 0.f, 0.f);
}

// ---- prep: pa_w (8,co,ci,9)->(8,ci,9,co); exp_w (320,32)->(32,320); pw_w (o,c)->(c,o)
__global__ void prep_kernel(const float* __restrict__ pa_w, const float* __restrict__ exp_w,
                            const float* __restrict__ pw_w, float* __restrict__ wt,
                            float* __restrict__ ewt, float* __restrict__ pwt) {
  int i = blockIdx.x * 256 + threadIdx.x;
  if (i < 73728) {
    int tap = i % 9; int t = i / 9;
    int ci = t & 31; t >>= 5;
    int co = t & 31; int layer = t >> 5;
    wt[((layer * 32 + ci) * 9 + tap) * 32 + co] = pa_w[i];
  } else if (i < 83968) {
    int j = i - 73728; int ci = j & 31; int o = j >> 5;
    ewt[ci * 320 + o] = exp_w[j];
  } else if (i < 84992) {
    int j = i - 83968; int c = j & 31; int o = j >> 5;
    pwt[c * 32 + o] = pw_w[j];
  }
}

// ---- avgpool k=4: x(B,C,512,512) -> feat0p interior
__global__ void avgpool4_kernel(const float* __restrict__ x, float* __restrict__ outp) {
  int idx = blockIdx.x * 256 + threadIdx.x;
  if (idx >= BATCH * NCH * 128 * 128) return;
  int ow = idx & 127; int t = idx >> 7; int oh = t & 127; int bc = t >> 7;
  const float* src = x + ((size_t)(bc * 512 + oh * 4)) * 512 + ow * 4;
  float s = 0.f;
#pragma unroll
  for (int r = 0; r < 4; r++) {
    float4 v = *reinterpret_cast<const float4*>(src + (size_t)r * 512);
    s += v.x + v.y + v.z + v.w;
  }
  outp[(size_t)bc * CS128 + (size_t)(oh + 1) * SP128 + ow + 4] = s * 0.0625f;
}

// ---- avgpool k=2: feat0p interior -> feat1p interior
__global__ void avgpool2_kernel(const float* __restrict__ inp, float* __restrict__ outp) {
  int idx = blockIdx.x * 256 + threadIdx.x;
  if (idx >= BATCH * NCH * 64 * 64) return;
  int ow = idx & 63; int t = idx >> 6; int oh = t & 63; int bc = t >> 6;
  const float* sp = inp + (size_t)bc * CS128 + (size_t)(2 * oh + 1) * SP128 + 2 * ow + 4;
  float2 a = *reinterpret_cast<const float2*>(sp);
  float2 b = *reinterpret_cast<const float2*>(sp + SP128);
  outp[(size_t)bc * CS64 + (size_t)(oh + 1) * SP64 + ow + 4] = (a.x + a.y + b.x + b.y) * 0.25f;
}

// ---- conv3x3 direct, 2 VERTICAL px/thread (R16 config).
template <int HS, int SP, int CS, int NCO, bool RELU, bool RES>
__global__ __launch_bounds__(256) void conv3x3v_kernel(
    const float* __restrict__ in, const float* __restrict__ wt,
    const float* __restrict__ bias, const float* __restrict__ res,
    float* __restrict__ out) {
  constexpr int TX = HS / 16;
  constexpr int TY = HS / 32;
  constexpr int GROUPS = 32 / NCO;
  int blk = blockIdx.x;
  int g = blk % GROUPS; int rest = blk / GROUPS;
  int b = rest / (TX * TY); int t = rest % (TX * TY);
  int ty = t / TX, tx = t % TX;
  int og = g * NCO;
  int px = threadIdx.x & 15, py = threadIdx.x >> 4;
  int gy = ty * 32 + py * 2, gx = tx * 16 + px;
  size_t pix = (size_t)(gy + 1) * SP + gx + 4;
  const float* inb = in + (size_t)b * 32 * CS + pix;

  float acc0[NCO], acc1[NCO];
#pragma unroll
  for (int o = 0; o < NCO; o++) { acc0[o] = bias[og + o]; acc1[o] = acc0[o]; }

#pragma unroll 2
  for (int ci = 0; ci < 32; ci++) {
    const float* p = inb + (size_t)ci * CS;
    float v[12];
    v[0] = p[-SP - 1];    v[1] = p[-SP];     v[2] = p[-SP + 1];
    v[3] = p[-1];         v[4] = p[0];       v[5] = p[1];
    v[6] = p[SP - 1];     v[7] = p[SP];      v[8] = p[SP + 1];
    v[9] = p[2 * SP - 1]; v[10] = p[2 * SP]; v[11] = p[2 * SP + 1];
    const float* wr = wt + ci * 288 + og;
#pragma unroll
    for (int tap = 0; tap < 9; tap++) {
      const float* wrow = wr + tap * 32;
#pragma unroll
      for (int o = 0; o < NCO; o++) {
        acc0[o] = fmaf(v[tap], wrow[o], acc0[o]);
        acc1[o] = fmaf(v[tap + 3], wrow[o], acc1[o]);
      }
    }
  }

  float* ob = out + (size_t)b * 32 * CS + (size_t)og * CS + pix;
  const float* rb = RES ? (res + (size_t)b * 32 * CS + (size_t)og * CS + pix) : nullptr;
#pragma unroll
  for (int o = 0; o < NCO; o++) {
    float r0 = acc0[o], r1 = acc1[o];
    if (RELU) { r0 = r0 > 0.f ? r0 : 0.01f * r0; r1 = r1 > 0.f ? r1 : 0.01f * r1; }
    if (RES) { r0 += rb[(size_t)o * CS]; r1 += rb[(size_t)o * CS + SP]; }
    ob[(size_t)o * CS] = r0;
    ob[(size_t)o * CS + SP] = r1;
  }
}

// ---- conv3x3 direct 1px (@64, R16 config).
template <int HS, int SP, int CS, int NCO, bool RELU, bool RES>
__global__ __launch_bounds__(256) void conv3x3d_kernel(
    const float* __restrict__ in, const float* __restrict__ wt,
    const float* __restrict__ bias, const float* __restrict__ res,
    float* __restrict__ out) {
  constexpr int TILES = HS / 16;
  constexpr int GROUPS = 32 / NCO;
  int blk = blockIdx.x;
  int g = blk % GROUPS; int rest = blk / GROUPS;
  int b = rest / (TILES * TILES); int t = rest % (TILES * TILES);
  int ty = t / TILES, tx = t % TILES;
  int og = g * NCO;
  int px = threadIdx.x & 15, py = threadIdx.x >> 4;
  int gy = ty * 16 + py, gx = tx * 16 + px;
  size_t pix = (size_t)(gy + 1) * SP + gx + 4;
  const float* inb = in + (size_t)b * 32 * CS + pix;

  float acc[NCO];
#pragma unroll
  for (int o = 0; o < NCO; o++) acc[o] = bias[og + o];

#pragma unroll 2
  for (int ci = 0; ci < 32; ci++) {
    const float* p = inb + (size_t)ci * CS;
    float v[9];
    v[0] = p[-SP - 1]; v[1] = p[-SP]; v[2] = p[-SP + 1];
    v[3] = p[-1];      v[4] = p[0];   v[5] = p[1];
    v[6] = p[SP - 1];  v[7] = p[SP];  v[8] = p[SP + 1];
    const float* wr = wt + ci * 288 + og;
#pragma unroll
    for (int tap = 0; tap < 9; tap++) {
      const float* wrow = wr + tap * 32;
#pragma unroll
      for (int o = 0; o < NCO; o++)
        acc[o] = fmaf(v[tap], wrow[o], acc[o]);
    }
  }

  float* ob = out + (size_t)b * 32 * CS + (size_t)og * CS + pix;
  const float* rb = RES ? (res + (size_t)b * 32 * CS + (size_t)og * CS + pix) : nullptr;
#pragma unroll
  for (int o = 0; o < NCO; o++) {
    float r2 = acc[o];
    if (RELU) r2 = r2 > 0.f ? r2 : 0.01f * r2;
    if (RES) r2 += rb[(size_t)o * CS];
    ob[(size_t)o * CS] = r2;
  }
}

// ---- expander 1x1 (32->320) + fast tanh, padded feat1p input.
__global__ __launch_bounds__(256) void expander_kernel(
    const float* __restrict__ feat, const float* __restrict__ ewt,
    const float* __restrict__ eb, float* __restrict__ wmap) {
  int idx = blockIdx.x * 256 + threadIdx.x;  // 1,310,720
  int wq = idx & 15; int t = idx >> 4;
  int o = t % 320; int rest = t / 320;
  int hb = rest & 63; int b = rest >> 6;
  const float* fp = feat + (size_t)b * 32 * CS64 + (size_t)(hb + 1) * SP64 + 4 + wq * 4;
  float s0 = eb[o];
  float s1 = s0, s2 = s0, s3 = s0;
#pragma unroll 8
  for (int ci = 0; ci < 32; ci++) {
    float4 f = *reinterpret_cast<const float4*>(fp + (size_t)ci * CS64);
    float wv = ewt[ci * 320 + o];
    s0 = fmaf(f.x, wv, s0); s1 = fmaf(f.y, wv, s1);
    s2 = fmaf(f.z, wv, s2); s3 = fmaf(f.w, wv, s3);
  }
  float4 r;
  r.x = fast_tanh(s0); r.y = fast_tanh(s1);
  r.z = fast_tanh(s2); r.w = fast_tanh(s3);
  *reinterpret_cast<float4*>(wmap + (size_t)((b * 64 + hb) * 320 + o) * 64 + wq * 4) = r;
}

// ---- flying conv, NO accumulator: c-iterations fully independent.
// Thread = 4 horizontal px; per c: 9 independent requests -> 36 FMA -> 1 float4
// store into OUT (per-channel fly result; pw pass sums in place afterwards).
// 128-thread blocks, 2048 blocks; s_w in LDS (conflict-free broadcast reads).
__global__ __launch_bounds__(128) void fly_kernel(
    const float* __restrict__ x, const float* __restrict__ wmap,
    float* __restrict__ out) {
  __shared__ float s_w[8][322];
  int blk = blockIdx.x;  // ((b*64+hb)*8 + wtile)
  int wtile = blk & 7; int t = blk >> 3; int hb = t & 63; int b = t >> 6;
  int tid = threadIdx.x;

  const float* wsrc = wmap + (size_t)(b * 64 + hb) * 320 * 64 + wtile * 8;
#pragma unroll
  for (int j = 0; j < 20; j++) {
    int idx = j * 128 + tid;
    int tap = idx >> 3, wb8 = idx & 7;
    s_w[wb8][tap] = wsrc[(size_t)tap * 64 + wb8];
  }
  __syncthreads();

  int p = tid & 15, row = tid >> 4;
  int h = hb * 8 + row;
  int w0 = wtile * 64 + 4 * p;
  int wbl = p >> 1;
  const float* xb = x + (size_t)b * 32 * 262144;
  float* ob = out + (size_t)b * 32 * 262144 + (size_t)h * 512 + w0;
  bool wl_ok = (w0 > 0), wr_ok = (w0 < 508);
  int hm = h - 1, hp = h + 1;
  bool okA = (hm >= 0), okC = (hp < 512);
  float4 z4 = make_float4(0.f, 0.f, 0.f, 0.f);

#pragma unroll 2
  for (int c = 0; c < 32; c++) {
    const float* wp = &s_w[wbl][c * 10];
    float wv0 = wp[0], wv1 = wp[1], wv2 = wp[2], wv3 = wp[3], wv4 = wp[4];
    float wv5 = wp[5], wv6 = wp[6], wv7 = wp[7], wv8 = wp[8], wv9 = wp[9];

    const float* xc = xb + (size_t)c * 262144;
    const float* pA = xc + (size_t)hm * 512 + w0;
    const float* pB = xc + (size_t)h * 512 + w0;
    const float* pC = xc + (size_t)hp * 512 + w0;
    float4 mA = okA ? *reinterpret_cast<const float4*>(pA) : z4;
    float4 mB = *reinterpret_cast<const float4*>(pB);
    float4 mC = okC ? *reinterpret_cast<const float4*>(pC) : z4;
    float lA = (okA && wl_ok) ? pA[-1] : 0.f;
    float lB = wl_ok ? pB[-1] : 0.f;
    float lC = (okC && wl_ok) ? pC[-1] : 0.f;
    float rA = (okA && wr_ok) ? pA[4] : 0.f;
    float rB = wr_ok ? pB[4] : 0.f;
    float rC = (okC && wr_ok) ? pC[4] : 0.f;

    float f0 = wv9, f1 = wv9, f2 = wv9, f3 = wv9;
    f0 = fmaf(lA,   wv0, f0); f0 = fmaf(mA.x, wv1, f0); f0 = fmaf(mA.y, wv2, f0);
    f0 = fmaf(lB,   wv3, f0); f0 = fmaf(mB.x, wv4, f0); f0 = fmaf(mB.y, wv5, f0);
    f0 = fmaf(lC,   wv6, f0); f0 = fmaf(mC.x, wv7, f0); f0 = fmaf(mC.y, wv8, f0);
    f1 = fmaf(mA.x, wv0, f1); f1 = fmaf(mA.y, wv1, f1); f1 = fmaf(mA.z, wv2, f1);
    f1 = fmaf(mB.x, wv3, f1); f1 = fmaf(mB.y, wv4, f1); f1 = fmaf(mB.z, wv5, f1);
    f1 = fmaf(mC.x, wv6, f1); f1 = fmaf(mC.y, wv7, f1); f1 = fmaf(mC.z, wv8, f1);
    f2 = fmaf(mA.y, wv0, f2); f2 = fmaf(mA.z, wv1, f2); f2 = fmaf(mA.w, wv2, f2);
    f2 = fmaf(mB.y, wv3, f2); f2 = fmaf(mB.z, wv4, f2); f2 = fmaf(mB.w, wv5, f2);
    f2 = fmaf(mC.y, wv6, f2); f2 = fmaf(mC.z, wv7, f2); f2 = fmaf(mC.w, wv8, f2);
    f3 = fmaf(mA.z, wv0, f3); f3 = fmaf(mA.w, wv1, f3); f3 = fmaf(rA,   wv2, f3);
    f3 = fmaf(mB.z, wv3, f3); f3 = fmaf(mB.w, wv4, f3); f3 = fmaf(rB,   wv5, f3);
    f3 = fmaf(mC.z, wv6, f3); f3 = fmaf(mC.w, wv7, f3); f3 = fmaf(rC,   wv8, f3);

    *reinterpret_cast<float4*>(ob + (size_t)c * 262144) = make_float4(f0, f1, f2, f3);
  }
}

// ---- final 1x1 conv IN-PLACE on out (R3-proven). Thread = one pixel column.
__global__ __launch_bounds__(256) void pw_inplace_kernel(
    const float* __restrict__ pwt, const float* __restrict__ pw_b,
    float* __restrict__ out) {
  int idx = blockIdx.x * 256 + threadIdx.x;  // B*512*512
  size_t base = (size_t)(idx >> 18) * 32 * 262144 + (idx & 262143);
  float f[32];
#pragma unroll
  for (int c = 0; c < 32; c++) f[c] = out[base + (size_t)c * 262144];
  float acc[32];
#pragma unroll
  for (int o = 0; o < 32; o++) acc[o] = pw_b[o];
  for (int c = 0; c < 32; c++) {
    const float* wrow = pwt + c * 32;
#pragma unroll
    for (int o = 0; o < 32; o++)
      acc[o] = fmaf(f[c], wrow[o], acc[o]);
  }
#pragma unroll
  for (int o = 0; o < 32; o++) out[base + (size_t)o * 262144] = acc[o];
}

extern "C" void kernel_launch(void* const* d_in, const int* in_sizes, int n_in,
                              void* d_out, int out_size, void* d_ws, size_t ws_size,
                              hipStream_t stream) {
  const float* x     = (const float*)d_in[0];
  const float* pa_w  = (const float*)d_in[1];
  const float* pa_b  = (const float*)d_in[2];
  const float* exp_w = (const float*)d_in[3];
  const float* exp_b = (const float*)d_in[4];
  const float* pw_w  = (const float*)d_in[5];
  const float* pw_b  = (const float*)d_in[6];
  float* out = (float*)d_out;
  float* ws  = (float*)d_ws;

  float* feat0p = ws;                    // 4*32*130*136 = 2,263,040
  float* tmpAp  = feat0p + 2263040;      // 2,263,040
  float* feat1p = tmpAp + 2263040;       // 4*32*66*72 = 608,256
  float* wmap   = feat1p + 608256;       // 5,242,880
  float* tmpBp  = wmap;                  // aliases wmap (dead before expander writes)
  float* wt     = wmap + 5242880;        // 73,728
  float* ewt    = wt + 73728;            // 10,240
  float* pwt    = ewt + 10240;           // 1,024

  hipLaunchKernelGGL(zero_kernel, dim3(5608), dim3(256), 0, stream, ws);
  hipLaunchKernelGGL(prep_kernel, dim3(332), dim3(256), 0, stream, pa_w, exp_w, pw_w, wt, ewt, pwt);
  hipLaunchKernelGGL(avgpool4_kernel, dim3(8192), dim3(256), 0, stream, x, feat0p);

  // predictors @128: 2-vert-px, NCO=4 -> 1024 blocks
  for (int i = 0; i < 2; i++) {
    const float* w1 = wt + (size_t)(i * 2 + 0) * 9216;
    const float* b1 = pa_b + (i * 2 + 0) * 32;
    const float* w2 = wt + (size_t)(i * 2 + 1) * 9216;
    const float* b2 = pa_b + (i * 2 + 1) * 32;
    hipLaunchKernelGGL((conv3x3v_kernel<128, SP128, CS128, 4, true, false>),
                       dim3(1024), dim3(256), 0, stream, feat0p, w1, b1, nullptr, tmpAp);
    hipLaunchKernelGGL((conv3x3v_kernel<128, SP128, CS128, 4, false, true>),
                       dim3(1024), dim3(256), 0, stream, tmpAp, w2, b2, feat0p, feat0p);
  }

  hipLaunchKernelGGL(avgpool2_kernel, dim3(2048), dim3(256), 0, stream, feat0p, feat1p);

  // predictors @64: NCO=2 -> 1024 blocks
  for (int i = 2; i < 4; i++) {
    const float* w1 = wt + (size_t)(i * 2 + 0) * 9216;
    const float* b1 = pa_b + (i * 2 + 0) * 32;
    const float* w2 = wt + (size_t)(i * 2 + 1) * 9216;
    const float* b2 = pa_b + (i * 2 + 1) * 32;
    hipLaunchKernelGGL((conv3x3d_kernel<64, SP64, CS64, 2, true, false>),
                       dim3(1024), dim3(256), 0, stream, feat1p, w1, b1, nullptr, tmpBp);
    hipLaunchKernelGGL((conv3x3d_kernel<64, SP64, CS64, 2, false, true>),
                       dim3(1024), dim3(256), 0, stream, tmpBp, w2, b2, feat1p, feat1p);
  }

  hipLaunchKernelGGL(expander_kernel, dim3(5120), dim3(256), 0, stream, feat1p, ewt, exp_b, wmap);

  hipLaunchKernelGGL(fly_kernel, dim3(2048), dim3(128), 0, stream, x, wmap, out);
  hipLaunchKernelGGL(pw_inplace_kernel, dim3(4096), dim3(256), 0, stream, pwt, pw_b, out);
}

// Round 20
// 338.605 us; speedup vs baseline: 1.3999x; 1.1796x over previous
//
#include <hip/hip_runtime.h>

// MalleConv: all f32. Head feature maps stored PADDED (zero halo).
// feat0p/tmpAp: (4,32,130,136) stride 136, interior [row+1][col+4], CS=17680
// feat1p/tmpBp: (4,32,66,72)   stride 72,  interior [row+1][col+4], CS=4752

#define BATCH 4
#define NCH 32
#define CS128 17680
#define SP128 136
#define CS64 4752
#define SP64 72

__device__ __forceinline__ float fast_tanh(float s) {
  float e = __expf(2.f * s);
  return fmaf(-2.f, __builtin_amdgcn_rcpf(e + 1.f), 1.f);
}

// ---- zero padded head buffers
__global__ void zero_kernel(float* __restrict__ p) {
  int i = blockIdx.x * 256 + threadIdx.x;  // 5608*256 = 1,435,648
  *reinterpret_cast<float4*>(p + (size_t)i * 4) = make_float4(0.f, 0.f, 0.f, 0.f);
}

// ---- prep: pa_w (8,co,ci,9)->(8,ci,9,co); exp_w (320,32)->(32,320); pw_w (o,c)->(c,o)
__global__ void prep_kernel(const float* __restrict__ pa_w, const float* __restrict__ exp_w,
                            const float* __restrict__ pw_w, float* __restrict__ wt,
                            float* __restrict__ ewt, float* __restrict__ pwt) {
  int i = blockIdx.x * 256 + threadIdx.x;
  if (i < 73728) {
    int tap = i % 9; int t = i / 9;
    int ci = t & 31; t >>= 5;
    int co = t & 31; int layer = t >> 5;
    wt[((layer * 32 + ci) * 9 + tap) * 32 + co] = pa_w[i];
  } else if (i < 83968) {
    int j = i - 73728; int ci = j & 31; int o = j >> 5;
    ewt[ci * 320 + o] = exp_w[j];
  } else if (i < 84992) {
    int j = i - 83968; int c = j & 31; int o = j >> 5;
    pwt[c * 32 + o] = pw_w[j];
  }
}

// ---- avgpool k=4: x(B,C,512,512) -> feat0p interior
__global__ void avgpool4_kernel(const float* __restrict__ x, float* __restrict__ outp) {
  int idx = blockIdx.x * 256 + threadIdx.x;
  if (idx >= BATCH * NCH * 128 * 128) return;
  int ow = idx & 127; int t = idx >> 7; int oh = t & 127; int bc = t >> 7;
  const float* src = x + ((size_t)(bc * 512 + oh * 4)) * 512 + ow * 4;
  float s = 0.f;
#pragma unroll
  for (int r = 0; r < 4; r++) {
    float4 v = *reinterpret_cast<const float4*>(src + (size_t)r * 512);
    s += v.x + v.y + v.z + v.w;
  }
  outp[(size_t)bc * CS128 + (size_t)(oh + 1) * SP128 + ow + 4] = s * 0.0625f;
}

// ---- avgpool k=2: feat0p interior -> feat1p interior
__global__ void avgpool2_kernel(const float* __restrict__ inp, float* __restrict__ outp) {
  int idx = blockIdx.x * 256 + threadIdx.x;
  if (idx >= BATCH * NCH * 64 * 64) return;
  int ow = idx & 63; int t = idx >> 6; int oh = t & 63; int bc = t >> 6;
  const float* sp = inp + (size_t)bc * CS128 + (size_t)(2 * oh + 1) * SP128 + 2 * ow + 4;
  float2 a = *reinterpret_cast<const float2*>(sp);
  float2 b = *reinterpret_cast<const float2*>(sp + SP128);
  outp[(size_t)bc * CS64 + (size_t)(oh + 1) * SP64 + ow + 4] = (a.x + a.y + b.x + b.y) * 0.25f;
}

// ---- conv3x3 direct, 4 VERTICAL px/thread (18 loads feed 144 FMAs per ci).
// Tile: 16 cols x 64 rows; 256 threads = 16 cols x 16 row-quads.
template <int HS, int SP, int CS, int NCO, bool RELU, bool RES>
__global__ __launch_bounds__(256) void conv3x3q_kernel(
    const float* __restrict__ in, const float* __restrict__ wt,
    const float* __restrict__ bias, const float* __restrict__ res,
    float* __restrict__ out) {
  constexpr int TX = HS / 16;
  constexpr int TY = HS / 64;
  constexpr int GROUPS = 32 / NCO;
  int blk = blockIdx.x;
  int g = blk % GROUPS; int rest = blk / GROUPS;
  int b = rest / (TX * TY); int t = rest % (TX * TY);
  int ty = t / TX, tx = t % TX;
  int og = g * NCO;
  int px = threadIdx.x & 15, py = threadIdx.x >> 4;
  int gy = ty * 64 + py * 4, gx = tx * 16 + px;
  size_t pix = (size_t)(gy + 1) * SP + gx + 4;
  const float* inb = in + (size_t)b * 32 * CS + pix;

  float acc[4][NCO];
#pragma unroll
  for (int q = 0; q < 4; q++)
#pragma unroll
    for (int o = 0; o < NCO; o++) acc[q][o] = bias[og + o];

#pragma unroll 2
  for (int ci = 0; ci < 32; ci++) {
    const float* p = inb + (size_t)ci * CS;
    float v[6][3];
#pragma unroll
    for (int r = 0; r < 6; r++) {
      const float* rp = p + (r - 1) * SP;
      v[r][0] = rp[-1]; v[r][1] = rp[0]; v[r][2] = rp[1];
    }
    const float* wr = wt + ci * 288 + og;
#pragma unroll
    for (int di = 0; di < 3; di++)
#pragma unroll
      for (int dj = 0; dj < 3; dj++) {
        const float* wrow = wr + (di * 3 + dj) * 32;
#pragma unroll
        for (int o = 0; o < NCO; o++) {
          float wv = wrow[o];
#pragma unroll
          for (int q = 0; q < 4; q++)
            acc[q][o] = fmaf(v[q + di][dj], wv, acc[q][o]);
        }
      }
  }

  float* ob = out + (size_t)b * 32 * CS + (size_t)og * CS + pix;
  const float* rb = RES ? (res + (size_t)b * 32 * CS + (size_t)og * CS + pix) : nullptr;
#pragma unroll
  for (int o = 0; o < NCO; o++)
#pragma unroll
    for (int q = 0; q < 4; q++) {
      float r2 = acc[q][o];
      if (RELU) r2 = r2 > 0.f ? r2 : 0.01f * r2;
      if (RES) r2 += rb[(size_t)o * CS + q * SP];
      ob[(size_t)o * CS + q * SP] = r2;
    }
}

// ---- conv3x3 direct 1px (@64, R16 config).
template <int HS, int SP, int CS, int NCO, bool RELU, bool RES>
__global__ __launch_bounds__(256) void conv3x3d_kernel(
    const float* __restrict__ in, const float* __restrict__ wt,
    const float* __restrict__ bias, const float* __restrict__ res,
    float* __restrict__ out) {
  constexpr int TILES = HS / 16;
  constexpr int GROUPS = 32 / NCO;
  int blk = blockIdx.x;
  int g = blk % GROUPS; int rest = blk / GROUPS;
  int b = rest / (TILES * TILES); int t = rest % (TILES * TILES);
  int ty = t / TILES, tx = t % TILES;
  int og = g * NCO;
  int px = threadIdx.x & 15, py = threadIdx.x >> 4;
  int gy = ty * 16 + py, gx = tx * 16 + px;
  size_t pix = (size_t)(gy + 1) * SP + gx + 4;
  const float* inb = in + (size_t)b * 32 * CS + pix;

  float acc[NCO];
#pragma unroll
  for (int o = 0; o < NCO; o++) acc[o] = bias[og + o];

#pragma unroll 2
  for (int ci = 0; ci < 32; ci++) {
    const float* p = inb + (size_t)ci * CS;
    float v[9];
    v[0] = p[-SP - 1]; v[1] = p[-SP]; v[2] = p[-SP + 1];
    v[3] = p[-1];      v[4] = p[0];   v[5] = p[1];
    v[6] = p[SP - 1];  v[7] = p[SP];  v[8] = p[SP + 1];
    const float* wr = wt + ci * 288 + og;
#pragma unroll
    for (int tap = 0; tap < 9; tap++) {
      const float* wrow = wr + tap * 32;
#pragma unroll
      for (int o = 0; o < NCO; o++)
        acc[o] = fmaf(v[tap], wrow[o], acc[o]);
    }
  }

  float* ob = out + (size_t)b * 32 * CS + (size_t)og * CS + pix;
  const float* rb = RES ? (res + (size_t)b * 32 * CS + (size_t)og * CS + pix) : nullptr;
#pragma unroll
  for (int o = 0; o < NCO; o++) {
    float r2 = acc[o];
    if (RELU) r2 = r2 > 0.f ? r2 : 0.01f * r2;
    if (RES) r2 += rb[(size_t)o * CS];
    ob[(size_t)o * CS] = r2;
  }
}

// ---- expander 1x1 (32->320) + fast tanh, padded feat1p input.
__global__ __launch_bounds__(256) void expander_kernel(
    const float* __restrict__ feat, const float* __restrict__ ewt,
    const float* __restrict__ eb, float* __restrict__ wmap) {
  int idx = blockIdx.x * 256 + threadIdx.x;  // 1,310,720
  int wq = idx & 15; int t = idx >> 4;
  int o = t % 320; int rest = t / 320;
  int hb = rest & 63; int b = rest >> 6;
  const float* fp = feat + (size_t)b * 32 * CS64 + (size_t)(hb + 1) * SP64 + 4 + wq * 4;
  float s0 = eb[o];
  float s1 = s0, s2 = s0, s3 = s0;
#pragma unroll 8
  for (int ci = 0; ci < 32; ci++) {
    float4 f = *reinterpret_cast<const float4*>(fp + (size_t)ci * CS64);
    float wv = ewt[ci * 320 + o];
    s0 = fmaf(f.x, wv, s0); s1 = fmaf(f.y, wv, s1);
    s2 = fmaf(f.z, wv, s2); s3 = fmaf(f.w, wv, s3);
  }
  float4 r;
  r.x = fast_tanh(s0); r.y = fast_tanh(s1);
  r.z = fast_tanh(s2); r.w = fast_tanh(s3);
  *reinterpret_cast<float4*>(wmap + (size_t)((b * 64 + hb) * 320 + o) * 64 + wq * 4) = r;
}

// ---- fused flying conv + final 1x1, v11: per-row taps from TWO aligned
// float4 loads (L @ w0-4 gives x[w0-1]=L.w; M @ w0 gives x[w0..w0+2]).
// 6 VMEM/c-iter vs v7's 9. Predicated fallbacks only at image edges.
__global__ __launch_bounds__(256) void fused_fly_pw_kernel(
    const float* __restrict__ x, const float* __restrict__ wmap,
    const float* __restrict__ pwt, const float* __restrict__ pw_b,
    float* __restrict__ out) {
  __shared__ float s_w[8][322];
  int blk = blockIdx.x;  // ((b*64+hb)*8 + wtile)
  int wtile = blk & 7; int t = blk >> 3; int hb = t & 63; int b = t >> 6;
  int tid = threadIdx.x;

  const float* wsrc = wmap + (size_t)(b * 64 + hb) * 320 * 64 + wtile * 8;
#pragma unroll
  for (int j = 0; j < 10; j++) {
    int idx = j * 256 + tid;
    int tap = idx >> 3, wb8 = idx & 7;
    s_w[wb8][tap] = wsrc[(size_t)tap * 64 + wb8];
  }
  __syncthreads();

  int p = tid & 31, row = tid >> 5;
  int h = hb * 8 + row;
  int w0 = wtile * 64 + 2 * p;
  int wbl = p >> 2;
  const float* xb = x + (size_t)b * 32 * 262144;
  bool l4_ok = (w0 >= 4);
  bool wl_ok = (w0 > 0);
  bool m4_ok = (w0 < 510);

  float2 acc[32];
#pragma unroll
  for (int o = 0; o < 32; o++) {
    float bv = pw_b[o];
    acc[o].x = bv; acc[o].y = bv;
  }

  for (int c = 0; c < 32; c++) {
    const float2* w2p = reinterpret_cast<const float2*>(&s_w[wbl][c * 10]);
    float2 w01 = w2p[0], w23 = w2p[1], w45 = w2p[2], w67 = w2p[3], w89 = w2p[4];
    float wv[9];
    wv[0] = w01.x; wv[1] = w01.y; wv[2] = w23.x;
    wv[3] = w23.y; wv[4] = w45.x; wv[5] = w45.y;
    wv[6] = w67.x; wv[7] = w67.y; wv[8] = w89.x;
    float fly0 = w89.y, fly1 = w89.y;  // bias tap

    const float* xc = xb + (size_t)c * 262144;
#pragma unroll
    for (int di = 0; di < 3; di++) {
      int hh = h + di - 1;
      if (hh < 0 || hh >= 512) continue;
      const float* rp = xc + (size_t)hh * 512 + w0;
      float lv;
      if (l4_ok) {
        float4 L = *reinterpret_cast<const float4*>(rp - 4);
        lv = L.w;
      } else {
        lv = wl_ok ? rp[-1] : 0.f;
      }
      float4 M;
      if (m4_ok) {
        M = *reinterpret_cast<const float4*>(rp);
      } else {
        float2 tm = *reinterpret_cast<const float2*>(rp);
        M = make_float4(tm.x, tm.y, 0.f, 0.f);
      }
      float wa = wv[di * 3 + 0], wb_ = wv[di * 3 + 1], wc = wv[di * 3 + 2];
      fly0 = fmaf(lv,  wa, fly0); fly0 = fmaf(M.x, wb_, fly0); fly0 = fmaf(M.y, wc, fly0);
      fly1 = fmaf(M.x, wa, fly1); fly1 = fmaf(M.y, wb_, fly1); fly1 = fmaf(M.z, wc, fly1);
    }
    const float* prow = pwt + c * 32;
#pragma unroll
    for (int o = 0; o < 32; o++) {
      float pw = prow[o];
      acc[o].x = fmaf(fly0, pw, acc[o].x);
      acc[o].y = fmaf(fly1, pw, acc[o].y);
    }
  }
  float* ob = out + (size_t)b * 32 * 262144 + (size_t)h * 512 + w0;
#pragma unroll
  for (int o = 0; o < 32; o++)
    *reinterpret_cast<float2*>(ob + (size_t)o * 262144) = acc[o];
}

extern "C" void kernel_launch(void* const* d_in, const int* in_sizes, int n_in,
                              void* d_out, int out_size, void* d_ws, size_t ws_size,
                              hipStream_t stream) {
  const float* x     = (const float*)d_in[0];
  const float* pa_w  = (const float*)d_in[1];
  const float* pa_b  = (const float*)d_in[2];
  const float* exp_w = (const float*)d_in[3];
  const float* exp_b = (const float*)d_in[4];
  const float* pw_w  = (const float*)d_in[5];
  const float* pw_b  = (const float*)d_in[6];
  float* out = (float*)d_out;
  float* ws  = (float*)d_ws;

  float* feat0p = ws;                    // 4*32*130*136 = 2,263,040
  float* tmpAp  = feat0p + 2263040;      // 2,263,040
  float* feat1p = tmpAp + 2263040;       // 4*32*66*72 = 608,256
  float* wmap   = feat1p + 608256;       // 5,242,880
  float* tmpBp  = wmap;                  // aliases wmap (dead before expander writes)
  float* wt     = wmap + 5242880;        // 73,728
  float* ewt    = wt + 73728;            // 10,240
  float* pwt    = ewt + 10240;           // 1,024

  hipLaunchKernelGGL(zero_kernel, dim3(5608), dim3(256), 0, stream, ws);
  hipLaunchKernelGGL(prep_kernel, dim3(332), dim3(256), 0, stream, pa_w, exp_w, pw_w, wt, ewt, pwt);
  hipLaunchKernelGGL(avgpool4_kernel, dim3(8192), dim3(256), 0, stream, x, feat0p);

  // predictors @128: 4-vert-px, NCO=4 -> 4b * 16 tiles * 8 groups = 512 blocks
  for (int i = 0; i < 2; i++) {
    const float* w1 = wt + (size_t)(i * 2 + 0) * 9216;
    const float* b1 = pa_b + (i * 2 + 0) * 32;
    const float* w2 = wt + (size_t)(i * 2 + 1) * 9216;
    const float* b2 = pa_b + (i * 2 + 1) * 32;
    hipLaunchKernelGGL((conv3x3q_kernel<128, SP128, CS128, 4, true, false>),
                       dim3(512), dim3(256), 0, stream, feat0p, w1, b1, nullptr, tmpAp);
    hipLaunchKernelGGL((conv3x3q_kernel<128, SP128, CS128, 4, false, true>),
                       dim3(512), dim3(256), 0, stream, tmpAp, w2, b2, feat0p, feat0p);
  }

  hipLaunchKernelGGL(avgpool2_kernel, dim3(2048), dim3(256), 0, stream, feat0p, feat1p);

  // predictors @64: NCO=2 -> 1024 blocks
  for (int i = 2; i < 4; i++) {
    const float* w1 = wt + (size_t)(i * 2 + 0) * 9216;
    const float* b1 = pa_b + (i * 2 + 0) * 32;
    const float* w2 = wt + (size_t)(i * 2 + 1) * 9216;
    const float* b2 = pa_b + (i * 2 + 1) * 32;
    hipLaunchKernelGGL((conv3x3d_kernel<64, SP64, CS64, 2, true, false>),
                       dim3(1024), dim3(256), 0, stream, feat1p, w1, b1, nullptr, tmpBp);
    hipLaunchKernelGGL((conv3x3d_kernel<64, SP64, CS64, 2, false, true>),
                       dim3(1024), dim3(256), 0, stream, tmpBp, w2, b2, feat1p, feat1p);
  }

  hipLaunchKernelGGL(expander_kernel, dim3(5120), dim3(256), 0, stream, feat1p, ewt, exp_b, wmap);

  hipLaunchKernelGGL(fused_fly_pw_kernel, dim3(2048), dim3(256), 0, stream,
                     x, wmap, pwt, pw_b, out);
}

// Round 21
// 337.955 us; speedup vs baseline: 1.4026x; 1.0019x over previous
//
#include <hip/hip_runtime.h>

// MalleConv: all f32. Head feature maps stored PADDED (zero halo).
// feat0p/tmpAp: (4,32,130,136) stride 136, interior [row+1][col+4], CS=17680
// feat1p/tmpBp: (4,32,66,72)   stride 72,  interior [row+1][col+4], CS=4752

#define BATCH 4
#define NCH 32
#define CS128 17680
#define SP128 136
#define CS64 4752
#define SP64 72

__device__ __forceinline__ float fast_tanh(float s) {
  float e = __expf(2.f * s);
  return fmaf(-2.f, __builtin_amdgcn_rcpf(e + 1.f), 1.f);
}

// ---- zero padded head buffers
__global__ void zero_kernel(float* __restrict__ p) {
  int i = blockIdx.x * 256 + threadIdx.x;  // 5608*256 = 1,435,648
  *reinterpret_cast<float4*>(p + (size_t)i * 4) = make_float4(0.f, 0.f, 0.f, 0.f);
}

// ---- prep: pa_w (8,co,ci,9)->(8,ci,9,co); exp_w (320,32)->(32,320); pw_w (o,c)->(c,o)
__global__ void prep_kernel(const float* __restrict__ pa_w, const float* __restrict__ exp_w,
                            const float* __restrict__ pw_w, float* __restrict__ wt,
                            float* __restrict__ ewt, float* __restrict__ pwt) {
  int i = blockIdx.x * 256 + threadIdx.x;
  if (i < 73728) {
    int tap = i % 9; int t = i / 9;
    int ci = t & 31; t >>= 5;
    int co = t & 31; int layer = t >> 5;
    wt[((layer * 32 + ci) * 9 + tap) * 32 + co] = pa_w[i];
  } else if (i < 83968) {
    int j = i - 73728; int ci = j & 31; int o = j >> 5;
    ewt[ci * 320 + o] = exp_w[j];
  } else if (i < 84992) {
    int j = i - 83968; int c = j & 31; int o = j >> 5;
    pwt[c * 32 + o] = pw_w[j];
  }
}

// ---- avgpool k=4: x(B,C,512,512) -> feat0p interior
__global__ void avgpool4_kernel(const float* __restrict__ x, float* __restrict__ outp) {
  int idx = blockIdx.x * 256 + threadIdx.x;
  if (idx >= BATCH * NCH * 128 * 128) return;
  int ow = idx & 127; int t = idx >> 7; int oh = t & 127; int bc = t >> 7;
  const float* src = x + ((size_t)(bc * 512 + oh * 4)) * 512 + ow * 4;
  float s = 0.f;
#pragma unroll
  for (int r = 0; r < 4; r++) {
    float4 v = *reinterpret_cast<const float4*>(src + (size_t)r * 512);
    s += v.x + v.y + v.z + v.w;
  }
  outp[(size_t)bc * CS128 + (size_t)(oh + 1) * SP128 + ow + 4] = s * 0.0625f;
}

// ---- avgpool k=2: feat0p interior -> feat1p interior
__global__ void avgpool2_kernel(const float* __restrict__ inp, float* __restrict__ outp) {
  int idx = blockIdx.x * 256 + threadIdx.x;
  if (idx >= BATCH * NCH * 64 * 64) return;
  int ow = idx & 63; int t = idx >> 6; int oh = t & 63; int bc = t >> 6;
  const float* sp = inp + (size_t)bc * CS128 + (size_t)(2 * oh + 1) * SP128 + 2 * ow + 4;
  float2 a = *reinterpret_cast<const float2*>(sp);
  float2 b = *reinterpret_cast<const float2*>(sp + SP128);
  outp[(size_t)bc * CS64 + (size_t)(oh + 1) * SP64 + ow + 4] = (a.x + a.y + b.x + b.y) * 0.25f;
}

// ---- conv3x3 direct, 2 VERTICAL px/thread, WEIGHTS STAGED IN LDS.
// Inner loop reads weights via uniform-address ds_read (broadcast) instead of
// per-iteration global/scalar loads -- removes the 36-load/iter weight stream.
template <int HS, int SP, int CS, int NCO, bool RELU, bool RES>
__global__ __launch_bounds__(256) void conv3x3v_kernel(
    const float* __restrict__ in, const float* __restrict__ wt,
    const float* __restrict__ bias, const float* __restrict__ res,
    float* __restrict__ out) {
  constexpr int TX = HS / 16;
  constexpr int TY = HS / 32;
  constexpr int GROUPS = 32 / NCO;
  __shared__ float s_wt[288 * NCO];
  int blk = blockIdx.x;
  int g = blk % GROUPS; int rest = blk / GROUPS;
  int b = rest / (TX * TY); int t = rest % (TX * TY);
  int ty = t / TX, tx = t % TX;
  int og = g * NCO;
  int tid = threadIdx.x;

  for (int i = tid; i < 288 * NCO; i += 256) {
    int pos = i / NCO, o = i - pos * NCO;   // pos = ci*9+tap
    s_wt[i] = wt[pos * 32 + og + o];
  }
  __syncthreads();

  int px = tid & 15, py = tid >> 4;
  int gy = ty * 32 + py * 2, gx = tx * 16 + px;
  size_t pix = (size_t)(gy + 1) * SP + gx + 4;
  const float* inb = in + (size_t)b * 32 * CS + pix;

  float acc0[NCO], acc1[NCO];
#pragma unroll
  for (int o = 0; o < NCO; o++) { acc0[o] = bias[og + o]; acc1[o] = acc0[o]; }

#pragma unroll 2
  for (int ci = 0; ci < 32; ci++) {
    const float* p = inb + (size_t)ci * CS;
    float v[12];
    v[0] = p[-SP - 1];    v[1] = p[-SP];     v[2] = p[-SP + 1];
    v[3] = p[-1];         v[4] = p[0];       v[5] = p[1];
    v[6] = p[SP - 1];     v[7] = p[SP];      v[8] = p[SP + 1];
    v[9] = p[2 * SP - 1]; v[10] = p[2 * SP]; v[11] = p[2 * SP + 1];
    const float* wr = s_wt + ci * 9 * NCO;
#pragma unroll
    for (int tap = 0; tap < 9; tap++) {
      const float* wrow = wr + tap * NCO;
#pragma unroll
      for (int o = 0; o < NCO; o++) {
        float wv = wrow[o];
        acc0[o] = fmaf(v[tap], wv, acc0[o]);
        acc1[o] = fmaf(v[tap + 3], wv, acc1[o]);
      }
    }
  }

  float* ob = out + (size_t)b * 32 * CS + (size_t)og * CS + pix;
  const float* rb = RES ? (res + (size_t)b * 32 * CS + (size_t)og * CS + pix) : nullptr;
#pragma unroll
  for (int o = 0; o < NCO; o++) {
    float r0 = acc0[o], r1 = acc1[o];
    if (RELU) { r0 = r0 > 0.f ? r0 : 0.01f * r0; r1 = r1 > 0.f ? r1 : 0.01f * r1; }
    if (RES) { r0 += rb[(size_t)o * CS]; r1 += rb[(size_t)o * CS + SP]; }
    ob[(size_t)o * CS] = r0;
    ob[(size_t)o * CS + SP] = r1;
  }
}

// ---- conv3x3 direct 1px (@64), WEIGHTS STAGED IN LDS.
template <int HS, int SP, int CS, int NCO, bool RELU, bool RES>
__global__ __launch_bounds__(256) void conv3x3d_kernel(
    const float* __restrict__ in, const float* __restrict__ wt,
    const float* __restrict__ bias, const float* __restrict__ res,
    float* __restrict__ out) {
  constexpr int TILES = HS / 16;
  constexpr int GROUPS = 32 / NCO;
  __shared__ float s_wt[288 * NCO];
  int blk = blockIdx.x;
  int g = blk % GROUPS; int rest = blk / GROUPS;
  int b = rest / (TILES * TILES); int t = rest % (TILES * TILES);
  int ty = t / TILES, tx = t % TILES;
  int og = g * NCO;
  int tid = threadIdx.x;

  for (int i = tid; i < 288 * NCO; i += 256) {
    int pos = i / NCO, o = i - pos * NCO;
    s_wt[i] = wt[pos * 32 + og + o];
  }
  __syncthreads();

  int px = tid & 15, py = tid >> 4;
  int gy = ty * 16 + py, gx = tx * 16 + px;
  size_t pix = (size_t)(gy + 1) * SP + gx + 4;
  const float* inb = in + (size_t)b * 32 * CS + pix;

  float acc[NCO];
#pragma unroll
  for (int o = 0; o < NCO; o++) acc[o] = bias[og + o];

#pragma unroll 2
  for (int ci = 0; ci < 32; ci++) {
    const float* p = inb + (size_t)ci * CS;
    float v[9];
    v[0] = p[-SP - 1]; v[1] = p[-SP]; v[2] = p[-SP + 1];
    v[3] = p[-1];      v[4] = p[0];   v[5] = p[1];
    v[6] = p[SP - 1];  v[7] = p[SP];  v[8] = p[SP + 1];
    const float* wr = s_wt + ci * 9 * NCO;
#pragma unroll
    for (int tap = 0; tap < 9; tap++) {
      const float* wrow = wr + tap * NCO;
#pragma unroll
      for (int o = 0; o < NCO; o++)
        acc[o] = fmaf(v[tap], wrow[o], acc[o]);
    }
  }

  float* ob = out + (size_t)b * 32 * CS + (size_t)og * CS + pix;
  const float* rb = RES ? (res + (size_t)b * 32 * CS + (size_t)og * CS + pix) : nullptr;
#pragma unroll
  for (int o = 0; o < NCO; o++) {
    float r2 = acc[o];
    if (RELU) r2 = r2 > 0.f ? r2 : 0.01f * r2;
    if (RES) r2 += rb[(size_t)o * CS];
    ob[(size_t)o * CS] = r2;
  }
}

// ---- expander 1x1 (32->320) + fast tanh, padded feat1p input.
__global__ __launch_bounds__(256) void expander_kernel(
    const float* __restrict__ feat, const float* __restrict__ ewt,
    const float* __restrict__ eb, float* __restrict__ wmap) {
  int idx = blockIdx.x * 256 + threadIdx.x;  // 1,310,720
  int wq = idx & 15; int t = idx >> 4;
  int o = t % 320; int rest = t / 320;
  int hb = rest & 63; int b = rest >> 6;
  const float* fp = feat + (size_t)b * 32 * CS64 + (size_t)(hb + 1) * SP64 + 4 + wq * 4;
  float s0 = eb[o];
  float s1 = s0, s2 = s0, s3 = s0;
#pragma unroll 8
  for (int ci = 0; ci < 32; ci++) {
    float4 f = *reinterpret_cast<const float4*>(fp + (size_t)ci * CS64);
    float wv = ewt[ci * 320 + o];
    s0 = fmaf(f.x, wv, s0); s1 = fmaf(f.y, wv, s1);
    s2 = fmaf(f.z, wv, s2); s3 = fmaf(f.w, wv, s3);
  }
  float4 r;
  r.x = fast_tanh(s0); r.y = fast_tanh(s1);
  r.z = fast_tanh(s2); r.w = fast_tanh(s3);
  *reinterpret_cast<float4*>(wmap + (size_t)((b * 64 + hb) * 320 + o) * 64 + wq * 4) = r;
}

// ---- fused flying conv + final 1x1 (v11, R20 config).
__global__ __launch_bounds__(256) void fused_fly_pw_kernel(
    const float* __restrict__ x, const float* __restrict__ wmap,
    const float* __restrict__ pwt, const float* __restrict__ pw_b,
    float* __restrict__ out) {
  __shared__ float s_w[8][322];
  int blk = blockIdx.x;  // ((b*64+hb)*8 + wtile)
  int wtile = blk & 7; int t = blk >> 3; int hb = t & 63; int b = t >> 6;
  int tid = threadIdx.x;

  const float* wsrc = wmap + (size_t)(b * 64 + hb) * 320 * 64 + wtile * 8;
#pragma unroll
  for (int j = 0; j < 10; j++) {
    int idx = j * 256 + tid;
    int tap = idx >> 3, wb8 = idx & 7;
    s_w[wb8][tap] = wsrc[(size_t)tap * 64 + wb8];
  }
  __syncthreads();

  int p = tid & 31, row = tid >> 5;
  int h = hb * 8 + row;
  int w0 = wtile * 64 + 2 * p;
  int wbl = p >> 2;
  const float* xb = x + (size_t)b * 32 * 262144;
  bool l4_ok = (w0 >= 4);
  bool wl_ok = (w0 > 0);
  bool m4_ok = (w0 < 510);

  float2 acc[32];
#pragma unroll
  for (int o = 0; o < 32; o++) {
    float bv = pw_b[o];
    acc[o].x = bv; acc[o].y = bv;
  }

  for (int c = 0; c < 32; c++) {
    const float2* w2p = reinterpret_cast<const float2*>(&s_w[wbl][c * 10]);
    float2 w01 = w2p[0], w23 = w2p[1], w45 = w2p[2], w67 = w2p[3], w89 = w2p[4];
    float wv[9];
    wv[0] = w01.x; wv[1] = w01.y; wv[2] = w23.x;
    wv[3] = w23.y; wv[4] = w45.x; wv[5] = w45.y;
    wv[6] = w67.x; wv[7] = w67.y; wv[8] = w89.x;
    float fly0 = w89.y, fly1 = w89.y;  // bias tap

    const float* xc = xb + (size_t)c * 262144;
#pragma unroll
    for (int di = 0; di < 3; di++) {
      int hh = h + di - 1;
      if (hh < 0 || hh >= 512) continue;
      const float* rp = xc + (size_t)hh * 512 + w0;
      float lv;
      if (l4_ok) {
        float4 L = *reinterpret_cast<const float4*>(rp - 4);
        lv = L.w;
      } else {
        lv = wl_ok ? rp[-1] : 0.f;
      }
      float4 M;
      if (m4_ok) {
        M = *reinterpret_cast<const float4*>(rp);
      } else {
        float2 tm = *reinterpret_cast<const float2*>(rp);
        M = make_float4(tm.x, tm.y, 0.f, 0.f);
      }
      float wa = wv[di * 3 + 0], wb_ = wv[di * 3 + 1], wc = wv[di * 3 + 2];
      fly0 = fmaf(lv,  wa, fly0); fly0 = fmaf(M.x, wb_, fly0); fly0 = fmaf(M.y, wc, fly0);
      fly1 = fmaf(M.x, wa, fly1); fly1 = fmaf(M.y, wb_, fly1); fly1 = fmaf(M.z, wc, fly1);
    }
    const float* prow = pwt + c * 32;
#pragma unroll
    for (int o = 0; o < 32; o++) {
      float pw = prow[o];
      acc[o].x = fmaf(fly0, pw, acc[o].x);
      acc[o].y = fmaf(fly1, pw, acc[o].y);
    }
  }
  float* ob = out + (size_t)b * 32 * 262144 + (size_t)h * 512 + w0;
#pragma unroll
  for (int o = 0; o < 32; o++)
    *reinterpret_cast<float2*>(ob + (size_t)o * 262144) = acc[o];
}

extern "C" void kernel_launch(void* const* d_in, const int* in_sizes, int n_in,
                              void* d_out, int out_size, void* d_ws, size_t ws_size,
                              hipStream_t stream) {
  const float* x     = (const float*)d_in[0];
  const float* pa_w  = (const float*)d_in[1];
  const float* pa_b  = (const float*)d_in[2];
  const float* exp_w = (const float*)d_in[3];
  const float* exp_b = (const float*)d_in[4];
  const float* pw_w  = (const float*)d_in[5];
  const float* pw_b  = (const float*)d_in[6];
  float* out = (float*)d_out;
  float* ws  = (float*)d_ws;

  float* feat0p = ws;                    // 4*32*130*136 = 2,263,040
  float* tmpAp  = feat0p + 2263040;      // 2,263,040
  float* feat1p = tmpAp + 2263040;       // 4*32*66*72 = 608,256
  float* wmap   = feat1p + 608256;       // 5,242,880
  float* tmpBp  = wmap;                  // aliases wmap (dead before expander writes)
  float* wt     = wmap + 5242880;        // 73,728
  float* ewt    = wt + 73728;            // 10,240
  float* pwt    = ewt + 10240;           // 1,024

  hipLaunchKernelGGL(zero_kernel, dim3(5608), dim3(256), 0, stream, ws);
  hipLaunchKernelGGL(prep_kernel, dim3(332), dim3(256), 0, stream, pa_w, exp_w, pw_w, wt, ewt, pwt);
  hipLaunchKernelGGL(avgpool4_kernel, dim3(8192), dim3(256), 0, stream, x, feat0p);

  // predictors @128: 2-vert-px, NCO=4 -> 1024 blocks, LDS weights
  for (int i = 0; i < 2; i++) {
    const float* w1 = wt + (size_t)(i * 2 + 0) * 9216;
    const float* b1 = pa_b + (i * 2 + 0) * 32;
    const float* w2 = wt + (size_t)(i * 2 + 1) * 9216;
    const float* b2 = pa_b + (i * 2 + 1) * 32;
    hipLaunchKernelGGL((conv3x3v_kernel<128, SP128, CS128, 4, true, false>),
                       dim3(1024), dim3(256), 0, stream, feat0p, w1, b1, nullptr, tmpAp);
    hipLaunchKernelGGL((conv3x3v_kernel<128, SP128, CS128, 4, false, true>),
                       dim3(1024), dim3(256), 0, stream, tmpAp, w2, b2, feat0p, feat0p);
  }

  hipLaunchKernelGGL(avgpool2_kernel, dim3(2048), dim3(256), 0, stream, feat0p, feat1p);

  // predictors @64: NCO=2 -> 1024 blocks, LDS weights
  for (int i = 2; i < 4; i++) {
    const float* w1 = wt + (size_t)(i * 2 + 0) * 9216;
    const float* b1 = pa_b + (i * 2 + 0) * 32;
    const float* w2 = wt + (size_t)(i * 2 + 1) * 9216;
    const float* b2 = pa_b + (i * 2 + 1) * 32;
    hipLaunchKernelGGL((conv3x3d_kernel<64, SP64, CS64, 2, true, false>),
                       dim3(1024), dim3(256), 0, stream, feat1p, w1, b1, nullptr, tmpBp);
    hipLaunchKernelGGL((conv3x3d_kernel<64, SP64, CS64, 2, false, true>),
                       dim3(1024), dim3(256), 0, stream, tmpBp, w2, b2, feat1p, feat1p);
  }

  hipLaunchKernelGGL(expander_kernel, dim3(5120), dim3(256), 0, stream, feat1p, ewt, exp_b, wmap);

  hipLaunchKernelGGL(fused_fly_pw_kernel, dim3(2048), dim3(256), 0, stream,
                     x, wmap, pwt, pw_b, out);
}